// Round 4
// baseline (344.769 us; speedup 1.0000x reference)
//
#include <hip/hip_runtime.h>
#include <cstdint>
#include <cstddef>

// Problem constants
#define B_   4
#define S_   4096
#define H_   1024
#define NH_  16
#define D_   64
#define M_TOT (B_ * S_)    // 16384 rows of hidden
#define K_TOT H_           // 1024 reduction dim
#define N_TOT (3 * H_)     // 3072 = concat(Q,K,V) output cols
#define SCALE_ 0.125f      // 1/sqrt(64)
#define NCH 16             // chunks for global-attention online softmax
#define CH (S_ / NCH)      // 256 positions per chunk

typedef __bf16 bf16x8 __attribute__((ext_vector_type(8)));
typedef float  f32x4  __attribute__((ext_vector_type(4)));

__device__ __forceinline__ unsigned short f2b(float x) {
    unsigned int u = __float_as_uint(x);
    u += 0x7FFFu + ((u >> 16) & 1u);          // round-to-nearest-even
    return (unsigned short)(u >> 16);
}
__device__ __forceinline__ float b2f(unsigned int u) {   // u = bf16 bits in low 16
    return __uint_as_float(u << 16);
}
__device__ __forceinline__ void unp8(uint4 u, float* f) {
    f[0] = b2f(u.x & 0xffffu); f[1] = b2f(u.x >> 16);
    f[2] = b2f(u.y & 0xffffu); f[3] = b2f(u.y >> 16);
    f[4] = b2f(u.z & 0xffffu); f[5] = b2f(u.z >> 16);
    f[6] = b2f(u.w & 0xffffu); f[7] = b2f(u.w >> 16);
}
__device__ __forceinline__ unsigned int pack2(float lo, float hi) {
    return (unsigned int)f2b(lo) | ((unsigned int)f2b(hi) << 16);
}

// ------------------------------------------------- fused fp32->bf16 converts
// 8 floats per thread; also zero-inits the combine counters (ws is 0xAA-poisoned
// before every call, and this kernel is stream-ordered before attn_all).
__global__ __launch_bounds__(256) void cvt_all(const float* __restrict__ hs,
                                               const float* __restrict__ wq,
                                               const float* __restrict__ wk,
                                               const float* __restrict__ wv,
                                               unsigned short* __restrict__ Xb,
                                               unsigned short* __restrict__ Wb,
                                               int* __restrict__ cnt) {
    if (blockIdx.x == 0 && threadIdx.x < B_ * NH_) cnt[threadIdx.x] = 0;
    const int i = blockIdx.x * 256 + threadIdx.x;
    const int X8 = M_TOT * K_TOT / 8;          // 2097152 = 2^21
    const float4* sp;
    uint4* dp;
    int off;
    if (i < X8) {
        sp = (const float4*)hs;
        dp = (uint4*)Xb;
        off = i;
    } else {
        const int j = i - X8;
        const int w = j >> 17;                 // H*H/8 = 2^17
        off = j & 0x1ffff;
        sp = (const float4*)((w == 0) ? wq : (w == 1 ? wk : wv));
        dp = (uint4*)(Wb + (size_t)w * H_ * H_);
    }
    const float4 v0 = sp[off * 2];
    const float4 v1 = sp[off * 2 + 1];
    uint4 o;
    o.x = pack2(v0.x, v0.y);
    o.y = pack2(v0.z, v0.w);
    o.z = pack2(v1.x, v1.y);
    o.w = pack2(v1.z, v1.w);
    dp[off] = o;
}

// ---------------------------------------------------------------- QKV GEMM
// C[m,n] = sum_k A[m,k]*W[n,k] (+bias[n]) ; A: M x K bf16, W: N x K bf16, C: M x N bf16
// 128x128 tile, BK=64 staged as TWO independent 32-k panels, each with the
// round-3-verified zero-conflict XOR swizzle. 32 MFMAs per barrier pair
// (vs 16 at BK=32) -> barrier-drain stall per MFMA halved. LDS 32 KB;
// occupancy stays register-limited (~3 blocks/CU), unchanged.
__global__ __launch_bounds__(256) void gemm_qkv(const unsigned short* __restrict__ A,
                                                const unsigned short* __restrict__ W,
                                                const float* __restrict__ bq,
                                                const float* __restrict__ bk,
                                                const float* __restrict__ bv,
                                                unsigned short* __restrict__ C) {
    __shared__ unsigned short As[2][128 * 32] __attribute__((aligned(16)));
    __shared__ unsigned short Bs[2][128 * 32] __attribute__((aligned(16)));
    const int tid  = threadIdx.x;
    const int wid  = tid >> 6;
    const int lane = tid & 63;
    const int wm = wid >> 1, wn = wid & 1;
    const int m0 = blockIdx.y * 128;
    const int n0 = blockIdx.x * 128;

    f32x4 acc[4][4];
#pragma unroll
    for (int i = 0; i < 4; i++)
#pragma unroll
        for (int j = 0; j < 4; j++) acc[i][j] = (f32x4){0.f, 0.f, 0.f, 0.f};

    const int lrow = lane >> 2;                                 // 0..15 : row within 16-row slab
    const int lcol = (((lane & 3) ^ ((lrow >> 1) & 3))) * 8;    // swizzled k-chunk offset

    const int rl    = lane & 15;
    const int slot8 = ((lane >> 4) ^ ((rl >> 1) & 3)) * 8;      // element offset of 16B slot

    for (int k0 = 0; k0 < K_TOT; k0 += 64) {
#pragma unroll
        for (int p = 0; p < 2; p++) {
#pragma unroll
            for (int i = 0; i < 2; i++) {
                const int r0 = wid * 32 + i * 16;
                const unsigned short* ga = A + (size_t)(m0 + r0 + lrow) * K_TOT + k0 + p * 32 + lcol;
                __builtin_amdgcn_global_load_lds(
                    (const __attribute__((address_space(1))) void*)ga,
                    (__attribute__((address_space(3))) void*)&As[p][r0 * 32], 16, 0, 0);
                const unsigned short* gb = W + (size_t)(n0 + r0 + lrow) * K_TOT + k0 + p * 32 + lcol;
                __builtin_amdgcn_global_load_lds(
                    (const __attribute__((address_space(1))) void*)gb,
                    (__attribute__((address_space(3))) void*)&Bs[p][r0 * 32], 16, 0, 0);
            }
        }
        __syncthreads();

#pragma unroll
        for (int p = 0; p < 2; p++) {
            bf16x8 af[4], bfv[4];
#pragma unroll
            for (int mi = 0; mi < 4; mi++)
                af[mi] = *(const bf16x8*)&As[p][(wm * 64 + mi * 16 + rl) * 32 + slot8];
#pragma unroll
            for (int ni = 0; ni < 4; ni++)
                bfv[ni] = *(const bf16x8*)&Bs[p][(wn * 64 + ni * 16 + rl) * 32 + slot8];
#pragma unroll
            for (int mi = 0; mi < 4; mi++)
#pragma unroll
                for (int ni = 0; ni < 4; ni++)
                    acc[mi][ni] = __builtin_amdgcn_mfma_f32_16x16x32_bf16(af[mi], bfv[ni], acc[mi][ni], 0, 0, 0);
        }
        __syncthreads();
    }

    const int col_l = lane & 15;
    const int quad  = lane >> 4;
#pragma unroll
    for (int mi = 0; mi < 4; mi++) {
#pragma unroll
        for (int ni = 0; ni < 4; ni++) {
            const int gc = n0 + wn * 64 + ni * 16 + col_l;
            const float bias = (gc < H_) ? bq[gc] : (gc < 2 * H_ ? bk[gc - H_] : bv[gc - 2 * H_]);
#pragma unroll
            for (int i = 0; i < 4; i++) {
                const int gr = m0 + wm * 64 + mi * 16 + quad * 4 + i;
                C[(size_t)gr * N_TOT + gc] = f2b(acc[mi][ni][i] + bias);
            }
        }
    }
}

// ------------------------------------------------- fused attention
// grid: 4096 local-attn blocks + 1024 global-attn blocks, 256 thr each.
// Role A (id < 4096): one wave per sequence position s, 64 lanes cover all 16
//   heads (lane: h=lane>>2, 16 d-elems per lane). Fully-coalesced 2KB row
//   loads and a contiguous 4KB ctx row store.
// Role B: global-attention partial (one 256-key chunk); the last-finishing
//   chunk block per (b,h) combines the 16 partials (device-scope atomic+fence).
__global__ __launch_bounds__(256) void attn_all(const unsigned short* __restrict__ QKV,
                                                const float* __restrict__ mask,
                                                float* __restrict__ Pm,
                                                float* __restrict__ Pl,
                                                float* __restrict__ Po,
                                                int* __restrict__ cnt,
                                                float* __restrict__ ctx,
                                                float* __restrict__ lat) {
    const int id  = blockIdx.x;
    const int tid = threadIdx.x;

    if (id < 4096) {
        // ---------------- Role A: local attention ----------------
        const int b  = id >> 10;
        const int sc = id & 1023;
        const int w = tid >> 6, lane = tid & 63;
        const int s = 1 + sc * 4 + w;
        if (s >= S_) return;                   // only sc=1023,w=3
        const int h = lane >> 2, c = lane & 3;

        const size_t base  = (size_t)(b * S_ + s) * N_TOT + h * D_ + c * 16;
        const size_t base0 = (size_t)(b * S_) * N_TOT + h * D_ + c * 16;

        uint4 qa = *(const uint4*)(QKV + base);
        uint4 qb = *(const uint4*)(QKV + base + 8);
        uint4 ka = *(const uint4*)(QKV + base + H_);
        uint4 kb = *(const uint4*)(QKV + base + H_ + 8);
        uint4 ga = *(const uint4*)(QKV + base0 + H_);
        uint4 gb = *(const uint4*)(QKV + base0 + H_ + 8);
        float qf[16], kf[16], gf[16];
        unp8(qa, qf); unp8(qb, qf + 8);
        unp8(ka, kf); unp8(kb, kf + 8);
        unp8(ga, gf); unp8(gb, gf + 8);

        float ps = 0.f, pg = 0.f;
#pragma unroll
        for (int i = 0; i < 16; i++) { ps += qf[i] * kf[i]; pg += qf[i] * gf[i]; }
        ps += __shfl_xor(ps, 1, 64); ps += __shfl_xor(ps, 2, 64);
        pg += __shfl_xor(pg, 1, 64); pg += __shfl_xor(pg, 2, 64);
        ps *= SCALE_; pg *= SCALE_;
        const float mx = fmaxf(ps, pg);
        const float e0 = __expf(ps - mx), e1 = __expf(pg - mx);
        const float z = e0 + e1;
        const float p0 = e0 / z, p1 = e1 / z;

        uint4 va = *(const uint4*)(QKV + base + 2 * H_);
        uint4 vb = *(const uint4*)(QKV + base + 2 * H_ + 8);
        uint4 ua = *(const uint4*)(QKV + base0 + 2 * H_);
        uint4 ub = *(const uint4*)(QKV + base0 + 2 * H_ + 8);
        float vf[16], uf[16];
        unp8(va, vf); unp8(vb, vf + 8);
        unp8(ua, uf); unp8(ub, uf + 8);

        float* cp = ctx + (size_t)(b * S_ + s) * H_ + h * D_ + c * 16;
#pragma unroll
        for (int t = 0; t < 4; t++) {
            float4 o;
            o.x = p0 * vf[t * 4 + 0] + p1 * uf[t * 4 + 0];
            o.y = p0 * vf[t * 4 + 1] + p1 * uf[t * 4 + 1];
            o.z = p0 * vf[t * 4 + 2] + p1 * uf[t * 4 + 2];
            o.w = p0 * vf[t * 4 + 3] + p1 * uf[t * 4 + 3];
            ((float4*)cp)[t] = o;
        }
        if (c == 0) {
            float2 lp; lp.x = p0; lp.y = p1;
            ((float2*)(lat + ((size_t)(b * NH_ + h) * (S_ - 1) + (s - 1)) * 2))[0] = lp;
        }
        return;
    }

    // ---------------- Role B: global attention partial + combine ----------------
    const int j  = id - 4096;
    const int bh = j >> 4;
    const int chunk = j & 15;
    const int b = bh >> 4, h = bh & 15;
    const int w = tid >> 6, lane = tid & 63;

    __shared__ float gq_sh[D_];
    __shared__ float pr[CH];
    __shared__ float red[8];
    __shared__ float osum[4][D_];
    __shared__ int lastFlag;

    const unsigned short* gqp = QKV + (size_t)(b * S_) * N_TOT + h * D_;
    if (tid < D_) gq_sh[tid] = b2f(gqp[tid]);
    __syncthreads();

    const int s0 = chunk * CH;
    const int s  = s0 + tid;
    const uint4* kp4 = (const uint4*)(QKV + (size_t)(b * S_ + s) * N_TOT + H_ + h * D_);
    float acc = 0.f;
#pragma unroll
    for (int c = 0; c < 8; c++) {
        uint4 r = kp4[c];
        acc += b2f(r.x & 0xffffu) * gq_sh[c * 8 + 0];
        acc += b2f(r.x >> 16)     * gq_sh[c * 8 + 1];
        acc += b2f(r.y & 0xffffu) * gq_sh[c * 8 + 2];
        acc += b2f(r.y >> 16)     * gq_sh[c * 8 + 3];
        acc += b2f(r.z & 0xffffu) * gq_sh[c * 8 + 4];
        acc += b2f(r.z >> 16)     * gq_sh[c * 8 + 5];
        acc += b2f(r.w & 0xffffu) * gq_sh[c * 8 + 6];
        acc += b2f(r.w >> 16)     * gq_sh[c * 8 + 7];
    }
    const float sv = acc * SCALE_ + mask[b * S_ + s];

    float wmax = sv;
#pragma unroll
    for (int m = 32; m >= 1; m >>= 1) wmax = fmaxf(wmax, __shfl_xor(wmax, m, 64));
    if (lane == 0) red[w] = wmax;
    __syncthreads();
    const float bmax = fmaxf(fmaxf(red[0], red[1]), fmaxf(red[2], red[3]));

    const float p = __expf(sv - bmax);
    pr[tid] = p;
    float wsum = p;
#pragma unroll
    for (int m = 32; m >= 1; m >>= 1) wsum += __shfl_xor(wsum, m, 64);
    if (lane == 0) red[4 + w] = wsum;
    __syncthreads();   // publishes pr[] for phase 2
    const float bsum = red[4] + red[5] + red[6] + red[7];

    float o = 0.f;
    const int sbase = s0 + w * 64;
#pragma unroll 8
    for (int i = 0; i < 64; i++) {
        const int si = sbase + i;
        const float vv = b2f((unsigned int)QKV[(size_t)(b * S_ + si) * N_TOT + 2 * H_ + h * D_ + lane]);
        o += pr[w * 64 + i] * vv;
    }
    osum[w][lane] = o;
    __syncthreads();
    if (tid < D_) {
        const float ot = osum[0][tid] + osum[1][tid] + osum[2][tid] + osum[3][tid];
        Po[(size_t)(bh * NCH + chunk) * D_ + tid] = ot;
        if (tid == 0) {
            Pm[bh * NCH + chunk] = bmax;
            Pl[bh * NCH + chunk] = bsum;
        }
    }
    // last-arriving chunk block combines the NCH partials for this (b,h)
    if (tid == 0) {
        __threadfence();                               // release partials
        lastFlag = (atomicAdd(&cnt[bh], 1) == NCH - 1);
    }
    __syncthreads();
    if (lastFlag) {
        __threadfence();                               // acquire others' partials
        const int d = tid;
        if (d < D_) {
            float ms = -1e30f;
#pragma unroll
            for (int c = 0; c < NCH; c++) ms = fmaxf(ms, Pm[bh * NCH + c]);
            float z = 0.f, oo = 0.f;
#pragma unroll
            for (int c = 0; c < NCH; c++) {
                const float e = __expf(Pm[bh * NCH + c] - ms);
                z += Pl[bh * NCH + c] * e;
                oo += Po[(size_t)(bh * NCH + c) * D_ + d] * e;
            }
            ctx[(size_t)b * S_ * H_ + (size_t)h * D_ + d] = oo / z;
        }
    }
}

// ---------------------------------------------------------------- launcher
extern "C" void kernel_launch(void* const* d_in, const int* in_sizes, int n_in,
                              void* d_out, int out_size, void* d_ws, size_t ws_size,
                              hipStream_t stream) {
    const float* hs   = (const float*)d_in[0];
    const float* mask = (const float*)d_in[1];
    const float* Wq   = (const float*)d_in[2];
    const float* bq   = (const float*)d_in[3];
    const float* Wk   = (const float*)d_in[4];
    const float* bk   = (const float*)d_in[5];
    const float* Wv   = (const float*)d_in[6];
    const float* bv   = (const float*)d_in[7];

    float* out = (float*)d_out;                       // (B,S,H) fp32
    float* lat = out + (size_t)B_ * S_ * H_;          // (B,NH,S-1,1,2) fp32

    char* ws = (char*)d_ws;
    const size_t offXb  = 0;
    const size_t offWb  = offXb  + (size_t)M_TOT * K_TOT * 2;
    const size_t offQKV = offWb  + (size_t)3 * H_ * H_ * 2;
    const size_t offPm  = offQKV + (size_t)M_TOT * N_TOT * 2;
    const size_t offPl  = offPm  + (size_t)B_ * NH_ * NCH * 4;
    const size_t offPo  = offPl  + (size_t)B_ * NH_ * NCH * 4;
    const size_t offCnt = offPo  + (size_t)B_ * NH_ * NCH * D_ * 4;

    unsigned short* Xb  = (unsigned short*)(ws + offXb);
    unsigned short* Wb  = (unsigned short*)(ws + offWb);
    unsigned short* QKV = (unsigned short*)(ws + offQKV);
    float* Pm = (float*)(ws + offPm);
    float* Pl = (float*)(ws + offPl);
    float* Po = (float*)(ws + offPo);
    int*   cnt = (int*)(ws + offCnt);

    const int total8 = M_TOT * K_TOT / 8 + 3 * H_ * H_ / 8;   // 2490368, /256 exact
    hipLaunchKernelGGL(cvt_all, dim3(total8 / 256), dim3(256), 0, stream,
                       hs, Wq, Wk, Wv, Xb, Wb, cnt);
    hipLaunchKernelGGL(gemm_qkv, dim3(N_TOT / 128, M_TOT / 128), dim3(256), 0, stream,
                       Xb, Wb, bq, bk, bv, QKV);
    hipLaunchKernelGGL(attn_all, dim3(4096 + B_ * NH_ * NCH), dim3(256), 0, stream,
                       QKV, mask, Pm, Pl, Po, cnt, out, lat);
}

// Round 5
// 312.646 us; speedup vs baseline: 1.1027x; 1.1027x over previous
//
#include <hip/hip_runtime.h>
#include <cstdint>
#include <cstddef>

// Problem constants
#define B_   4
#define S_   4096
#define H_   1024
#define NH_  16
#define D_   64
#define M_TOT (B_ * S_)    // 16384 rows of hidden
#define K_TOT H_           // 1024 reduction dim
#define N_TOT (3 * H_)     // 3072 = concat(Q,K,V) output cols
#define SCALE_ 0.125f      // 1/sqrt(64)
#define NCH 32             // chunks for global-attention online softmax
#define CH (S_ / NCH)      // 128 positions per chunk

typedef __bf16 bf16x8 __attribute__((ext_vector_type(8)));
typedef float  f32x4  __attribute__((ext_vector_type(4)));

__device__ __forceinline__ unsigned short f2b(float x) {
    unsigned int u = __float_as_uint(x);
    u += 0x7FFFu + ((u >> 16) & 1u);          // round-to-nearest-even
    return (unsigned short)(u >> 16);
}
__device__ __forceinline__ float b2f(unsigned int u) {   // u = bf16 bits in low 16
    return __uint_as_float(u << 16);
}
__device__ __forceinline__ void unp8(uint4 u, float* f) {
    f[0] = b2f(u.x & 0xffffu); f[1] = b2f(u.x >> 16);
    f[2] = b2f(u.y & 0xffffu); f[3] = b2f(u.y >> 16);
    f[4] = b2f(u.z & 0xffffu); f[5] = b2f(u.z >> 16);
    f[6] = b2f(u.w & 0xffffu); f[7] = b2f(u.w >> 16);
}
__device__ __forceinline__ unsigned int pack2(float lo, float hi) {
    return (unsigned int)f2b(lo) | ((unsigned int)f2b(hi) << 16);
}

// ------------------------------------------------- fused fp32->bf16 converts
// 8 floats per thread: 2 float4 loads -> 1 uint4 (8 bf16) store.
__global__ __launch_bounds__(256) void cvt_all(const float* __restrict__ hs,
                                               const float* __restrict__ wq,
                                               const float* __restrict__ wk,
                                               const float* __restrict__ wv,
                                               unsigned short* __restrict__ Xb,
                                               unsigned short* __restrict__ Wb) {
    const int i = blockIdx.x * 256 + threadIdx.x;
    const int X8 = M_TOT * K_TOT / 8;          // 2097152 = 2^21
    const float4* sp;
    uint4* dp;
    int off;
    if (i < X8) {
        sp = (const float4*)hs;
        dp = (uint4*)Xb;
        off = i;
    } else {
        const int j = i - X8;
        const int w = j >> 17;                 // H*H/8 = 2^17
        off = j & 0x1ffff;
        sp = (const float4*)((w == 0) ? wq : (w == 1 ? wk : wv));
        dp = (uint4*)(Wb + (size_t)w * H_ * H_);
    }
    const float4 v0 = sp[off * 2];
    const float4 v1 = sp[off * 2 + 1];
    uint4 o;
    o.x = pack2(v0.x, v0.y);
    o.y = pack2(v0.z, v0.w);
    o.z = pack2(v1.x, v1.y);
    o.w = pack2(v1.z, v1.w);
    dp[off] = o;
}

// ---------------------------------------------------------------- QKV GEMM
// Round-3-proven version: 128x128 tile, BK=32, zero-conflict XOR swizzle
// (counter-verified SQ_LDS_BANK_CONFLICT == 0). BK=64 (round 4) was neutral:
// the vmcnt(0) barrier drain scales with staged bytes, so fewer barriers buy
// nothing — do not revisit within this 2-barrier structure.
__global__ __launch_bounds__(256) void gemm_qkv(const unsigned short* __restrict__ A,
                                                const unsigned short* __restrict__ W,
                                                const float* __restrict__ bq,
                                                const float* __restrict__ bk,
                                                const float* __restrict__ bv,
                                                unsigned short* __restrict__ C) {
    __shared__ unsigned short As[128 * 32] __attribute__((aligned(16)));
    __shared__ unsigned short Bs[128 * 32] __attribute__((aligned(16)));
    const int tid  = threadIdx.x;
    const int wid  = tid >> 6;
    const int lane = tid & 63;
    const int wm = wid >> 1, wn = wid & 1;
    const int m0 = blockIdx.y * 128;
    const int n0 = blockIdx.x * 128;

    f32x4 acc[4][4];
#pragma unroll
    for (int i = 0; i < 4; i++)
#pragma unroll
        for (int j = 0; j < 4; j++) acc[i][j] = (f32x4){0.f, 0.f, 0.f, 0.f};

    const int lrow = lane >> 2;                                 // 0..15 : row within 16-row slab
    const int lcol = (((lane & 3) ^ ((lrow >> 1) & 3))) * 8;    // swizzled k-chunk offset

    const int rl    = lane & 15;
    const int slot8 = ((lane >> 4) ^ ((rl >> 1) & 3)) * 8;      // element offset of 16B slot

    for (int k0 = 0; k0 < K_TOT; k0 += 32) {
#pragma unroll
        for (int i = 0; i < 2; i++) {
            const int r0 = wid * 32 + i * 16;
            const unsigned short* ga = A + (size_t)(m0 + r0 + lrow) * K_TOT + k0 + lcol;
            __builtin_amdgcn_global_load_lds(
                (const __attribute__((address_space(1))) void*)ga,
                (__attribute__((address_space(3))) void*)&As[r0 * 32], 16, 0, 0);
            const unsigned short* gb = W + (size_t)(n0 + r0 + lrow) * K_TOT + k0 + lcol;
            __builtin_amdgcn_global_load_lds(
                (const __attribute__((address_space(1))) void*)gb,
                (__attribute__((address_space(3))) void*)&Bs[r0 * 32], 16, 0, 0);
        }
        __syncthreads();

        bf16x8 af[4], bfv[4];
#pragma unroll
        for (int mi = 0; mi < 4; mi++)
            af[mi] = *(const bf16x8*)&As[(wm * 64 + mi * 16 + rl) * 32 + slot8];
#pragma unroll
        for (int ni = 0; ni < 4; ni++)
            bfv[ni] = *(const bf16x8*)&Bs[(wn * 64 + ni * 16 + rl) * 32 + slot8];
#pragma unroll
        for (int mi = 0; mi < 4; mi++)
#pragma unroll
            for (int ni = 0; ni < 4; ni++)
                acc[mi][ni] = __builtin_amdgcn_mfma_f32_16x16x32_bf16(af[mi], bfv[ni], acc[mi][ni], 0, 0, 0);
        __syncthreads();
    }

    const int col_l = lane & 15;
    const int quad  = lane >> 4;
#pragma unroll
    for (int mi = 0; mi < 4; mi++) {
#pragma unroll
        for (int ni = 0; ni < 4; ni++) {
            const int gc = n0 + wn * 64 + ni * 16 + col_l;
            const float bias = (gc < H_) ? bq[gc] : (gc < 2 * H_ ? bk[gc - H_] : bv[gc - 2 * H_]);
#pragma unroll
            for (int i = 0; i < 4; i++) {
                const int gr = m0 + wm * 64 + mi * 16 + quad * 4 + i;
                C[(size_t)gr * N_TOT + gc] = f2b(acc[mi][ni][i] + bias);
            }
        }
    }
}

// ------------------------------------------------- global attention (s=0 query)
// grid (B*NH, NCH=32), 256 thr. Phase 1: threads 0..127 compute one key-dot
// each (full D=64). Phase 2: each of the 4 waves covers 32 keys of the PV sum.
// 2048 blocks -> 8 blocks/CU (round 5: doubled parallelism for this
// latency-bound kernel; NCH 4->16 previously saved ~25 us of tail).
__global__ __launch_bounds__(256) void gattn_part(const unsigned short* __restrict__ QKV,
                                                  const float* __restrict__ mask,
                                                  float* __restrict__ Pm,
                                                  float* __restrict__ Pl,
                                                  float* __restrict__ Po) {
    const int bh = blockIdx.x;
    const int b = bh >> 4, h = bh & 15;
    const int chunk = blockIdx.y;
    const int tid = threadIdx.x;
    const int w = tid >> 6, lane = tid & 63;

    __shared__ float gq_sh[D_];
    __shared__ float pr[CH];
    __shared__ float red[8];
    __shared__ float osum[4][D_];

    const unsigned short* gqp = QKV + (size_t)(b * S_) * N_TOT + h * D_;
    if (tid < D_) gq_sh[tid] = b2f(gqp[tid]);
    __syncthreads();

    const int s0 = chunk * CH;
    float sv = -1e30f;
    if (tid < CH) {
        const int s = s0 + tid;
        const uint4* kp4 = (const uint4*)(QKV + (size_t)(b * S_ + s) * N_TOT + H_ + h * D_);
        float acc = 0.f;
#pragma unroll
        for (int c = 0; c < 8; c++) {
            uint4 r = kp4[c];
            acc += b2f(r.x & 0xffffu) * gq_sh[c * 8 + 0];
            acc += b2f(r.x >> 16)     * gq_sh[c * 8 + 1];
            acc += b2f(r.y & 0xffffu) * gq_sh[c * 8 + 2];
            acc += b2f(r.y >> 16)     * gq_sh[c * 8 + 3];
            acc += b2f(r.z & 0xffffu) * gq_sh[c * 8 + 4];
            acc += b2f(r.z >> 16)     * gq_sh[c * 8 + 5];
            acc += b2f(r.w & 0xffffu) * gq_sh[c * 8 + 6];
            acc += b2f(r.w >> 16)     * gq_sh[c * 8 + 7];
        }
        sv = acc * SCALE_ + mask[b * S_ + s];
    }

    // block max over the 128 valid scores (waves 0,1)
    float wmax = sv;
#pragma unroll
    for (int m = 32; m >= 1; m >>= 1) wmax = fmaxf(wmax, __shfl_xor(wmax, m, 64));
    if (lane == 0 && w < 2) red[w] = wmax;
    __syncthreads();
    const float bmax = fmaxf(red[0], red[1]);

    float p = 0.f;
    if (tid < CH) {
        p = __expf(sv - bmax);
        pr[tid] = p;
    }
    float wsum = p;
#pragma unroll
    for (int m = 32; m >= 1; m >>= 1) wsum += __shfl_xor(wsum, m, 64);
    if (lane == 0 && w < 2) red[4 + w] = wsum;
    __syncthreads();   // publishes pr[] for phase 2
    const float bsum = red[4] + red[5];

    // o[d] = sum_s p[s] * v[s][d]; wave w covers 32 consecutive s
    float o = 0.f;
    const int sbase = s0 + w * 32;
#pragma unroll 8
    for (int i = 0; i < 32; i++) {
        const int si = sbase + i;
        const float vv = b2f((unsigned int)QKV[(size_t)(b * S_ + si) * N_TOT + 2 * H_ + h * D_ + lane]);
        o += pr[w * 32 + i] * vv;
    }
    osum[w][lane] = o;
    __syncthreads();
    if (tid < D_) {
        const float ot = osum[0][tid] + osum[1][tid] + osum[2][tid] + osum[3][tid];
        Po[(size_t)(bh * NCH + chunk) * D_ + tid] = ot;
        if (tid == 0) {
            Pm[bh * NCH + chunk] = bmax;
            Pl[bh * NCH + chunk] = bsum;
        }
    }
}

// ------------------------------------------------- local attention + combine
// grid (B*NH, 129), 256 thr. y<128: 4 waves; wave handles 8 s-positions with
// 8 lanes each (lane covers 8 d via one uint4 = 16B load). y==128: combine the
// NCH global-attention partials into ctx row s=0 (threads 0..63).
__global__ __launch_bounds__(256) void lattn(const unsigned short* __restrict__ QKV,
                                             float* __restrict__ ctx,
                                             float* __restrict__ lat,
                                             const float* __restrict__ Pm,
                                             const float* __restrict__ Pl,
                                             const float* __restrict__ Po) {
    const int bh = blockIdx.x;
    const int b = bh >> 4, h = bh & 15;

    if (blockIdx.y == 128) {
        const int d = threadIdx.x;
        if (d < D_) {
            float ms = -1e30f;
#pragma unroll
            for (int c = 0; c < NCH; c++) ms = fmaxf(ms, Pm[bh * NCH + c]);
            float z = 0.f, o = 0.f;
#pragma unroll
            for (int c = 0; c < NCH; c++) {
                const float e = __expf(Pm[bh * NCH + c] - ms);
                z += Pl[bh * NCH + c] * e;
                o += Po[(size_t)(bh * NCH + c) * D_ + d] * e;
            }
            ctx[(size_t)b * S_ * H_ + (size_t)h * D_ + d] = o / z;
        }
        return;
    }

    const int w = threadIdx.x >> 6, lane = threadIdx.x & 63;
    const int g = lane >> 3;     // s-subgroup within wave
    const int l = lane & 7;      // d-octet index
    const int s = 1 + blockIdx.y * 32 + w * 8 + g;
    if (s >= S_) return;         // only the very last 8-lane group; no later barriers

    const size_t rowS = (size_t)(b * S_ + s) * N_TOT + h * D_ + l * 8;
    const size_t row0 = (size_t)(b * S_) * N_TOT + h * D_ + l * 8;

    uint4 qu  = *(const uint4*)(QKV + rowS);
    uint4 ku  = *(const uint4*)(QKV + rowS + H_);
    uint4 k0u = *(const uint4*)(QKV + row0 + H_);
    float qf[8], kf[8], k0f[8];
    unp8(qu, qf); unp8(ku, kf); unp8(k0u, k0f);

    float ps = 0.f, pg = 0.f;
#pragma unroll
    for (int i = 0; i < 8; i++) { ps += qf[i] * kf[i]; pg += qf[i] * k0f[i]; }
#pragma unroll
    for (int m = 1; m < 8; m <<= 1) {   // reduce within the 8-lane d-group
        ps += __shfl_xor(ps, m, 64);
        pg += __shfl_xor(pg, m, 64);
    }
    ps *= SCALE_; pg *= SCALE_;
    const float mx = fmaxf(ps, pg);
    const float e0 = __expf(ps - mx), e1 = __expf(pg - mx);
    const float z = e0 + e1;
    const float p0 = e0 / z, p1 = e1 / z;

    uint4 vu  = *(const uint4*)(QKV + rowS + 2 * H_);
    uint4 v0u = *(const uint4*)(QKV + row0 + 2 * H_);
    float vf[8], v0f[8];
    unp8(vu, vf); unp8(v0u, v0f);

    float* cp = ctx + (size_t)b * (S_ * H_) + (size_t)s * H_ + h * D_ + l * 8;
    float4 o0, o1;
    o0.x = p0 * vf[0] + p1 * v0f[0];
    o0.y = p0 * vf[1] + p1 * v0f[1];
    o0.z = p0 * vf[2] + p1 * v0f[2];
    o0.w = p0 * vf[3] + p1 * v0f[3];
    o1.x = p0 * vf[4] + p1 * v0f[4];
    o1.y = p0 * vf[5] + p1 * v0f[5];
    o1.z = p0 * vf[6] + p1 * v0f[6];
    o1.w = p0 * vf[7] + p1 * v0f[7];
    ((float4*)cp)[0] = o0;
    ((float4*)cp)[1] = o1;

    if (l == 0) {
        float2 lp; lp.x = p0; lp.y = p1;
        ((float2*)(lat + ((size_t)bh * (S_ - 1) + (s - 1)) * 2))[0] = lp;
    }
}

// ---------------------------------------------------------------- launcher
extern "C" void kernel_launch(void* const* d_in, const int* in_sizes, int n_in,
                              void* d_out, int out_size, void* d_ws, size_t ws_size,
                              hipStream_t stream) {
    const float* hs   = (const float*)d_in[0];
    const float* mask = (const float*)d_in[1];
    const float* Wq   = (const float*)d_in[2];
    const float* bq   = (const float*)d_in[3];
    const float* Wk   = (const float*)d_in[4];
    const float* bk   = (const float*)d_in[5];
    const float* Wv   = (const float*)d_in[6];
    const float* bv   = (const float*)d_in[7];

    float* out = (float*)d_out;                       // (B,S,H) fp32
    float* lat = out + (size_t)B_ * S_ * H_;          // (B,NH,S-1,1,2) fp32

    char* ws = (char*)d_ws;
    const size_t offXb  = 0;
    const size_t offWb  = offXb  + (size_t)M_TOT * K_TOT * 2;
    const size_t offQKV = offWb  + (size_t)3 * H_ * H_ * 2;
    const size_t offPm  = offQKV + (size_t)M_TOT * N_TOT * 2;
    const size_t offPl  = offPm  + (size_t)B_ * NH_ * NCH * 4;
    const size_t offPo  = offPl  + (size_t)B_ * NH_ * NCH * 4;

    unsigned short* Xb  = (unsigned short*)(ws + offXb);
    unsigned short* Wb  = (unsigned short*)(ws + offWb);
    unsigned short* QKV = (unsigned short*)(ws + offQKV);
    float* Pm = (float*)(ws + offPm);
    float* Pl = (float*)(ws + offPl);
    float* Po = (float*)(ws + offPo);

    const int total8 = M_TOT * K_TOT / 8 + 3 * H_ * H_ / 8;   // 2490368, /256 exact
    hipLaunchKernelGGL(cvt_all, dim3(total8 / 256), dim3(256), 0, stream,
                       hs, Wq, Wk, Wv, Xb, Wb);
    hipLaunchKernelGGL(gemm_qkv, dim3(N_TOT / 128, M_TOT / 128), dim3(256), 0, stream,
                       Xb, Wb, bq, bk, bv, QKV);
    hipLaunchKernelGGL(gattn_part, dim3(B_ * NH_, NCH), dim3(256), 0, stream, QKV, mask, Pm, Pl, Po);
    hipLaunchKernelGGL(lattn, dim3(B_ * NH_, 129), dim3(256), 0, stream, QKV, out, lat, Pm, Pl, Po);
}